// Round 1
// baseline (155.314 us; speedup 1.0000x reference)
//
#include <hip/hip_runtime.h>

typedef __attribute__((ext_vector_type(8))) short bf16x8;
typedef __attribute__((ext_vector_type(4))) short s16x4;
typedef __attribute__((ext_vector_type(4))) float f32x4;
typedef __attribute__((ext_vector_type(4))) int   i32x4;

#define MFMA16 __builtin_amdgcn_mfma_f32_16x16x32_bf16

#define B_ 64
#define N_ 512
#define D_ 128

__device__ __forceinline__ unsigned short f2bf(float f) {
  unsigned u = __builtin_bit_cast(unsigned, f);
  u += 0x7fffu + ((u >> 16) & 1u);          // round-to-nearest-even
  return (unsigned short)(u >> 16);
}
__device__ __forceinline__ int packbf2(float lo, float hi) {
  return (int)((unsigned)f2bf(lo) | ((unsigned)f2bf(hi) << 16));
}

// ---------------- W -> bf16 prep ----------------
__global__ void prep_w(const float* __restrict__ Wk, const float* __restrict__ Wq,
                       short* __restrict__ wkb, short* __restrict__ wqb) {
  int i = blockIdx.x * 256 + threadIdx.x;
  if (i < D_ * D_) { wkb[i] = (short)f2bf(Wk[i]); wqb[i] = (short)f2bf(Wq[i]); }
}

// ---------------- projections: k = h@Wk^T+bk, q = h@Wq^T+bq (bf16 out, + kT) ----------------
// grid: 512 blocks x 256 thr; each wave: 32 rows x all 128 outputs (k,q) + kT.
__global__ __launch_bounds__(256, 2) void proj_kernel(
    const float* __restrict__ h1, const float* __restrict__ h2,
    const short* __restrict__ wkb, const short* __restrict__ wqb,
    const float* __restrict__ bk, const float* __restrict__ bq,
    short* __restrict__ k1, short* __restrict__ k2,
    short* __restrict__ q1, short* __restrict__ q2,
    short* __restrict__ k1T, short* __restrict__ k2T) {
  const int wave = threadIdx.x >> 6, lane = threadIdx.x & 63;
  const int c = lane & 15, g = lane >> 4;
  const int rw = blockIdx.x * 128 + wave * 32;   // global row base of this wave
  const int inp = rw >> 15;                      // 0: h1, 1: h2
  const int loc = rw & 32767;                    // row within input (= b*512+n)
  const int b = loc >> 9, n0 = loc & 511;
  const float* __restrict__ h = inp ? h2 : h1;
  short* __restrict__ kout = inp ? k2 : k1;
  short* __restrict__ qout = inp ? q2 : q1;
  short* __restrict__ kT   = inp ? k2T : k1T;

  // X fragments: lane=row (c), k = kk*32 + g*8 .. +7 (f32 -> bf16)
  bf16x8 xf[2][4];
#pragma unroll
  for (int mt = 0; mt < 2; ++mt) {
    const float* hr = h + (long)(loc + mt * 16 + c) * D_;
#pragma unroll
    for (int kk = 0; kk < 4; ++kk) {
      f32x4 lo = *(const f32x4*)(hr + kk * 32 + g * 8);
      f32x4 hi = *(const f32x4*)(hr + kk * 32 + g * 8 + 4);
      bf16x8 v;
      v[0] = (short)f2bf(lo[0]); v[1] = (short)f2bf(lo[1]);
      v[2] = (short)f2bf(lo[2]); v[3] = (short)f2bf(lo[3]);
      v[4] = (short)f2bf(hi[0]); v[5] = (short)f2bf(hi[1]);
      v[6] = (short)f2bf(hi[2]); v[7] = (short)f2bf(hi[3]);
      xf[mt][kk] = v;
    }
  }

#pragma unroll
  for (int et = 0; et < 8; ++et) {
    bf16x8 wkf[4], wqf[4];
    const short* wkr = wkb + (et * 16 + c) * D_;
    const short* wqr = wqb + (et * 16 + c) * D_;
#pragma unroll
    for (int kk = 0; kk < 4; ++kk) {
      wkf[kk] = *(const bf16x8*)(wkr + kk * 32 + g * 8);
      wqf[kk] = *(const bf16x8*)(wqr + kk * 32 + g * 8);
    }
    f32x4 ak[2], aq[2], at[2];
#pragma unroll
    for (int mt = 0; mt < 2; ++mt) {
      ak[mt] = (f32x4){0.f, 0.f, 0.f, 0.f};
      aq[mt] = (f32x4){0.f, 0.f, 0.f, 0.f};
      at[mt] = (f32x4){0.f, 0.f, 0.f, 0.f};
    }
#pragma unroll
    for (int kk = 0; kk < 4; ++kk) {
#pragma unroll
      for (int mt = 0; mt < 2; ++mt) {
        ak[mt] = MFMA16(wkf[kk], xf[mt][kk], ak[mt], 0, 0, 0);  // D: row=e_loc, col=h-row
        aq[mt] = MFMA16(wqf[kk], xf[mt][kk], aq[mt], 0, 0, 0);
        at[mt] = MFMA16(xf[mt][kk], wkf[kk], at[mt], 0, 0, 0);  // D: row=h-row, col=e_loc
      }
    }
    f32x4 bkv = *(const f32x4*)(bk + et * 16 + g * 4);
    f32x4 bqv = *(const f32x4*)(bq + et * 16 + g * 4);
    float bks = bk[et * 16 + c];
#pragma unroll
    for (int mt = 0; mt < 2; ++mt) {
      s16x4 pk, pq, pt;
#pragma unroll
      for (int j = 0; j < 4; ++j) {
        pk[j] = (short)f2bf(ak[mt][j] + bkv[j]);
        pq[j] = (short)f2bf(aq[mt][j] + bqv[j]);
        pt[j] = (short)f2bf(at[mt][j] + bks);
      }
      long row = (long)(loc + mt * 16 + c);
      *(s16x4*)(kout + row * D_ + et * 16 + g * 4) = pk;
      *(s16x4*)(qout + row * D_ + et * 16 + g * 4) = pq;
      *(s16x4*)(kT + ((long)(b * D_ + et * 16 + c)) * N_ + n0 + mt * 16 + g * 4) = pt;
    }
  }
}

// ---------------- attention ----------------
// grid (8, 64, 2): qtile, b, dir. block 256 = 4 waves x 16 q-rows.
// S^T = mfma(K,Q): lane&15 = q (lane-local softmax row), row = node-local.
__global__ __launch_bounds__(256, 2) void attn_kernel(
    const short* __restrict__ k1, const short* __restrict__ k2,
    const short* __restrict__ q1, const short* __restrict__ q2,
    const short* __restrict__ k1T, const short* __restrict__ k2T,
    const float* __restrict__ tptr,
    const int* __restrict__ len1, const int* __restrict__ len2,
    float* __restrict__ out) {
  const int wave = threadIdx.x >> 6, lane = threadIdx.x & 63;
  const int c = lane & 15, g = lane >> 4;
  const int qt = blockIdx.x, b = blockIdx.y, dir = blockIdx.z;
  const short* __restrict__ qp = dir ? q2 : q1;
  const short* __restrict__ kp = dir ? k1 : k2;
  const short* __restrict__ vT = dir ? k1T : k2T;
  const int lk = dir ? len1[b] : len2[b];  // column (key) validity
  const int lq = dir ? len2[b] : len1[b];  // row (query) validity
  float* __restrict__ o = out + (long)dir * B_ * N_ * D_;
  const float ts = *tptr;
  const int q0 = qt * 64 + wave * 16;

  // Q fragments (lane=q-row)
  bf16x8 qf[4];
  const short* qrow = qp + ((long)(b * N_ + q0 + c)) * D_;
#pragma unroll
  for (int kk = 0; kk < 4; ++kk) qf[kk] = *(const bf16x8*)(qrow + kk * 32 + g * 8);

  // S^T pass over 32 node-tiles
  f32x4 s[32];
  const short* kbase = kp + (long)b * N_ * D_;
#pragma unroll
  for (int t16 = 0; t16 < 32; ++t16) {
    const short* krow = kbase + (t16 * 16 + c) * D_;
    f32x4 acc = (f32x4){0.f, 0.f, 0.f, 0.f};
#pragma unroll
    for (int kk = 0; kk < 4; ++kk) {
      bf16x8 kf = *(const bf16x8*)(krow + kk * 32 + g * 8);
      acc = MFMA16(kf, qf[kk], acc, 0, 0, 0);
    }
    const int node = t16 * 16 + g * 4;
#pragma unroll
    for (int j = 0; j < 4; ++j) {
      float v = acc[j] * ts;
      s[t16][j] = (node + j < lk) ? v : -1e9f;
    }
  }

  // softmax (per q = lane&15; reduce over the 4 lane-groups)
  float mx = -3e38f;
#pragma unroll
  for (int t16 = 0; t16 < 32; ++t16)
#pragma unroll
    for (int j = 0; j < 4; ++j) mx = fmaxf(mx, s[t16][j]);
  mx = fmaxf(mx, __shfl_xor(mx, 16));
  mx = fmaxf(mx, __shfl_xor(mx, 32));
  float rs = 0.f;
#pragma unroll
  for (int t16 = 0; t16 < 32; ++t16)
#pragma unroll
    for (int j = 0; j < 4; ++j) {
      float p = __expf(s[t16][j] - mx);
      s[t16][j] = p;
      rs += p;
    }
  rs += __shfl_xor(rs, 16);
  rs += __shfl_xor(rs, 32);
  const float rinv = 1.0f / rs;

  // PV: o^T accumulate. P-frag built per 32-node chunk via cross-lane shuffles.
  f32x4 oacc[8];
#pragma unroll
  for (int dt = 0; dt < 8; ++dt) oacc[dt] = (f32x4){0.f, 0.f, 0.f, 0.f};
  const int srcA = c + ((g & 1) << 5);  // lane (c, 2*(g&1))
  const int srcB = srcA + 16;           // lane (c, 1+2*(g&1))
  const bool lowhalf = (g < 2);
  const short* vbase = vT + (long)b * D_ * N_;
#pragma unroll
  for (int ck = 0; ck < 16; ++ck) {
    int a0 = packbf2(s[2 * ck][0], s[2 * ck][1]);
    int a1 = packbf2(s[2 * ck][2], s[2 * ck][3]);
    int b0 = packbf2(s[2 * ck + 1][0], s[2 * ck + 1][1]);
    int b1 = packbf2(s[2 * ck + 1][2], s[2 * ck + 1][3]);
    int xa0 = __shfl(a0, srcA), xb0 = __shfl(b0, srcA);
    int xa1 = __shfl(a1, srcA), xb1 = __shfl(b1, srcA);
    int ya0 = __shfl(a0, srcB), yb0 = __shfl(b0, srcB);
    int ya1 = __shfl(a1, srcB), yb1 = __shfl(b1, srcB);
    i32x4 ui;
    ui[0] = lowhalf ? xa0 : xb0;
    ui[1] = lowhalf ? xa1 : xb1;
    ui[2] = lowhalf ? ya0 : yb0;
    ui[3] = lowhalf ? ya1 : yb1;
    bf16x8 pf = __builtin_bit_cast(bf16x8, ui);
#pragma unroll
    for (int dt = 0; dt < 8; ++dt) {
      bf16x8 vt = *(const bf16x8*)(vbase + (dt * 16 + c) * N_ + ck * 32 + g * 8);
      oacc[dt] = MFMA16(vt, pf, oacc[dt], 0, 0, 0);  // D: row=d_loc, col=q
    }
  }

  // epilogue: scale by 1/rowsum, zero invalid rows, coalesced f32x4 stores
  const int qg = q0 + c;
  const bool valid = qg < lq;
  float* orow = o + ((long)(b * N_ + qg)) * D_;
#pragma unroll
  for (int dt = 0; dt < 8; ++dt) {
    f32x4 vo;
#pragma unroll
    for (int j = 0; j < 4; ++j) vo[j] = valid ? oacc[dt][j] * rinv : 0.0f;
    *(f32x4*)(orow + dt * 16 + g * 4) = vo;
  }
}

extern "C" void kernel_launch(void* const* d_in, const int* in_sizes, int n_in,
                              void* d_out, int out_size, void* d_ws, size_t ws_size,
                              hipStream_t stream) {
  const float* h1 = (const float*)d_in[0];
  const float* h2 = (const float*)d_in[1];
  const float* Wk = (const float*)d_in[2];
  const float* bk = (const float*)d_in[3];
  const float* Wq = (const float*)d_in[4];
  const float* bq = (const float*)d_in[5];
  const float* t  = (const float*)d_in[6];
  const int* len1 = (const int*)d_in[7];
  const int* len2 = (const int*)d_in[8];

  char* ws = (char*)d_ws;
  const size_t SZ = (size_t)B_ * N_ * D_ * 2;  // 8,388,608 bytes per bf16 tensor
  short* k1  = (short*)(ws + 0 * SZ);
  short* k2  = (short*)(ws + 1 * SZ);
  short* q1  = (short*)(ws + 2 * SZ);
  short* q2  = (short*)(ws + 3 * SZ);
  short* k1T = (short*)(ws + 4 * SZ);
  short* k2T = (short*)(ws + 5 * SZ);
  short* wkb = (short*)(ws + 6 * SZ);
  short* wqb = (short*)(ws + 6 * SZ + D_ * D_ * 2);

  prep_w<<<64, 256, 0, stream>>>(Wk, Wq, wkb, wqb);
  proj_kernel<<<512, 256, 0, stream>>>(h1, h2, wkb, wqb, bk, bq,
                                       k1, k2, q1, q2, k1T, k2T);
  attn_kernel<<<dim3(8, 64, 2), 256, 0, stream>>>(k1, k2, q1, q2, k1T, k2T,
                                                  t, len1, len2, (float*)d_out);
}

// Round 2
// 84.976 us; speedup vs baseline: 1.8277x; 1.8277x over previous
//
#include <hip/hip_runtime.h>

typedef __attribute__((ext_vector_type(8))) short bf16x8;
typedef __attribute__((ext_vector_type(4))) short s16x4;
typedef __attribute__((ext_vector_type(4))) float f32x4;
typedef __attribute__((ext_vector_type(4))) int   i32x4;

#define MFMA16 __builtin_amdgcn_mfma_f32_16x16x32_bf16

#define B_ 64
#define N_ 512
#define D_ 128

__device__ __forceinline__ unsigned short f2bf(float f) {
  unsigned u = __builtin_bit_cast(unsigned, f);
  u += 0x7fffu + ((u >> 16) & 1u);          // round-to-nearest-even
  return (unsigned short)(u >> 16);
}
__device__ __forceinline__ int packbf2(float lo, float hi) {
  return (int)((unsigned)f2bf(lo) | ((unsigned)f2bf(hi) << 16));
}

__device__ __forceinline__ void gload_lds16(const void* g, void* l) {
  __builtin_amdgcn_global_load_lds((const __attribute__((address_space(1))) unsigned*)g,
                                   (__attribute__((address_space(3))) unsigned*)l, 16, 0, 0);
}

// ---------------- W -> bf16 prep ----------------
__global__ void prep_w(const float* __restrict__ Wk, const float* __restrict__ Wq,
                       short* __restrict__ wkb, short* __restrict__ wqb) {
  int i = blockIdx.x * 256 + threadIdx.x;
  if (i < D_ * D_) { wkb[i] = (short)f2bf(Wk[i]); wqb[i] = (short)f2bf(Wq[i]); }
}

// ---------------- projections: k = h@Wk^T+bk, q = h@Wq^T+bq (bf16 out, + kT) ----------------
__global__ __launch_bounds__(256, 2) void proj_kernel(
    const float* __restrict__ h1, const float* __restrict__ h2,
    const short* __restrict__ wkb, const short* __restrict__ wqb,
    const float* __restrict__ bk, const float* __restrict__ bq,
    short* __restrict__ k1, short* __restrict__ k2,
    short* __restrict__ q1, short* __restrict__ q2,
    short* __restrict__ k1T, short* __restrict__ k2T) {
  const int wave = threadIdx.x >> 6, lane = threadIdx.x & 63;
  const int c = lane & 15, g = lane >> 4;
  const int rw = blockIdx.x * 128 + wave * 32;
  const int inp = rw >> 15;
  const int loc = rw & 32767;
  const int b = loc >> 9, n0 = loc & 511;
  const float* __restrict__ h = inp ? h2 : h1;
  short* __restrict__ kout = inp ? k2 : k1;
  short* __restrict__ qout = inp ? q2 : q1;
  short* __restrict__ kT   = inp ? k2T : k1T;

  bf16x8 xf[2][4];
#pragma unroll
  for (int mt = 0; mt < 2; ++mt) {
    const float* hr = h + (long)(loc + mt * 16 + c) * D_;
#pragma unroll
    for (int kk = 0; kk < 4; ++kk) {
      f32x4 lo = *(const f32x4*)(hr + kk * 32 + g * 8);
      f32x4 hi = *(const f32x4*)(hr + kk * 32 + g * 8 + 4);
      bf16x8 v;
      v[0] = (short)f2bf(lo[0]); v[1] = (short)f2bf(lo[1]);
      v[2] = (short)f2bf(lo[2]); v[3] = (short)f2bf(lo[3]);
      v[4] = (short)f2bf(hi[0]); v[5] = (short)f2bf(hi[1]);
      v[6] = (short)f2bf(hi[2]); v[7] = (short)f2bf(hi[3]);
      xf[mt][kk] = v;
    }
  }

#pragma unroll
  for (int et = 0; et < 8; ++et) {
    bf16x8 wkf[4], wqf[4];
    const short* wkr = wkb + (et * 16 + c) * D_;
    const short* wqr = wqb + (et * 16 + c) * D_;
#pragma unroll
    for (int kk = 0; kk < 4; ++kk) {
      wkf[kk] = *(const bf16x8*)(wkr + kk * 32 + g * 8);
      wqf[kk] = *(const bf16x8*)(wqr + kk * 32 + g * 8);
    }
    f32x4 ak[2], aq[2], at[2];
#pragma unroll
    for (int mt = 0; mt < 2; ++mt) {
      ak[mt] = (f32x4){0.f, 0.f, 0.f, 0.f};
      aq[mt] = (f32x4){0.f, 0.f, 0.f, 0.f};
      at[mt] = (f32x4){0.f, 0.f, 0.f, 0.f};
    }
#pragma unroll
    for (int kk = 0; kk < 4; ++kk) {
#pragma unroll
      for (int mt = 0; mt < 2; ++mt) {
        ak[mt] = MFMA16(wkf[kk], xf[mt][kk], ak[mt], 0, 0, 0);
        aq[mt] = MFMA16(wqf[kk], xf[mt][kk], aq[mt], 0, 0, 0);
        at[mt] = MFMA16(xf[mt][kk], wkf[kk], at[mt], 0, 0, 0);
      }
    }
    f32x4 bkv = *(const f32x4*)(bk + et * 16 + g * 4);
    f32x4 bqv = *(const f32x4*)(bq + et * 16 + g * 4);
    float bks = bk[et * 16 + c];
#pragma unroll
    for (int mt = 0; mt < 2; ++mt) {
      s16x4 pk, pq, pt;
#pragma unroll
      for (int j = 0; j < 4; ++j) {
        pk[j] = (short)f2bf(ak[mt][j] + bkv[j]);
        pq[j] = (short)f2bf(aq[mt][j] + bqv[j]);
        pt[j] = (short)f2bf(at[mt][j] + bks);
      }
      long row = (long)(loc + mt * 16 + c);
      *(s16x4*)(kout + row * D_ + et * 16 + g * 4) = pk;
      *(s16x4*)(qout + row * D_ + et * 16 + g * 4) = pq;
      *(s16x4*)(kT + ((long)(b * D_ + et * 16 + c)) * N_ + n0 + mt * 16 + g * 4) = pt;
    }
  }
}

// ---------------- attention (LDS-staged, double-buffered, swizzled) ----------------
// grid (8, 64, 2): qtile, b, dir. block 256 = 4 waves x 16 q-rows each.
// Phase A: S^T over 8 chunks of 64 keys staged in LDS as [64][256B] (XOR-swizzled).
// Phase B: PV over 8 chunks of vT staged as [128][128B] (XOR-swizzled).
#define CH_ 64               // keys per chunk
#define NCH_ (N_ / CH_)      // 8 chunks
#define KBUF_ 16384          // bytes per buffer

__global__ __launch_bounds__(256, 2) void attn_kernel(
    const short* __restrict__ k1, const short* __restrict__ k2,
    const short* __restrict__ q1, const short* __restrict__ q2,
    const short* __restrict__ k1T, const short* __restrict__ k2T,
    const float* __restrict__ tptr,
    const int* __restrict__ len1, const int* __restrict__ len2,
    float* __restrict__ out) {
  extern __shared__ char smem[];
  const int tid = threadIdx.x;
  const int wave = tid >> 6, lane = tid & 63;
  const int c = lane & 15, g = lane >> 4;
  const int qt = blockIdx.x, b = blockIdx.y, dir = blockIdx.z;
  const short* __restrict__ qp = dir ? q2 : q1;
  const short* __restrict__ kp = dir ? k1 : k2;
  const short* __restrict__ vT = dir ? k1T : k2T;
  const int lk = dir ? len1[b] : len2[b];
  const int lq = dir ? len2[b] : len1[b];
  float* __restrict__ o = out + (long)dir * B_ * N_ * D_;
  const float ts = *tptr;
  const int q0 = qt * 64 + wave * 16;

  const char* kbase = (const char*)(kp + (long)b * N_ * D_);       // [512][256B]
  const char* vbase = (const char*)(vT + (long)b * D_ * N_);       // [128][1024B]

  // ---- stage helpers (inverse-swizzled global source, linear LDS dest) ----
  // K chunk ch: 64 rows x 256B from kbase + ch*64*256
  auto stage_k = [&](int ch, char* buf) {
#pragma unroll
    for (int i = 0; i < 4; ++i) {
      int L = i * 4096 + tid * 16;
      int row = L >> 8, off = L & 255;
      int srco = off ^ ((row & 7) << 4);
      const char* gp = kbase + (ch * 64 + row) * 256 + srco;
      char* lp = buf + i * 4096 + (wave << 10);   // wave-uniform base
      gload_lds16(gp, lp);
    }
  };
  // vT chunk ch: 128 rows x 128B from vbase + ch*128 (col offset)
  auto stage_v = [&](int ch, char* buf) {
#pragma unroll
    for (int i = 0; i < 4; ++i) {
      int L = i * 4096 + tid * 16;
      int row = L >> 7, off = L & 127;
      int srco = off ^ ((row & 7) << 4);
      const char* gp = vbase + row * 1024 + ch * 128 + srco;
      char* lp = buf + i * 4096 + (wave << 10);
      gload_lds16(gp, lp);
    }
  };

  // Q fragments (lane=q-row)
  bf16x8 qf[4];
  const short* qrow = qp + ((long)(b * N_ + q0 + c)) * D_;
#pragma unroll
  for (int kk = 0; kk < 4; ++kk) qf[kk] = *(const bf16x8*)(qrow + kk * 32 + g * 8);

  // ---- Phase A: S^T ----
  f32x4 s[32];
  stage_k(0, smem);
  __syncthreads();
#pragma unroll
  for (int ch = 0; ch < NCH_; ++ch) {
    if (ch + 1 < NCH_) stage_k(ch + 1, smem + KBUF_ * ((ch + 1) & 1));
    const char* buf = smem + KBUF_ * (ch & 1);
#pragma unroll
    for (int tl = 0; tl < 4; ++tl) {
      int r = tl * 16 + c;
      const char* base = buf + (r << 8);
      int sw = (r & 7) << 4;
      f32x4 acc = (f32x4){0.f, 0.f, 0.f, 0.f};
#pragma unroll
      for (int kk = 0; kk < 4; ++kk) {
        bf16x8 kf = *(const bf16x8*)(base + ((kk * 64 + g * 16) ^ sw));
        acc = MFMA16(kf, qf[kk], acc, 0, 0, 0);
      }
      const int node = ch * 64 + tl * 16 + g * 4;
#pragma unroll
      for (int j = 0; j < 4; ++j) {
        float v = acc[j] * ts;
        s[ch * 4 + tl][j] = (node + j < lk) ? v : -1e9f;
      }
    }
    __syncthreads();
  }

  // stage first vT chunk; DMA hides under the register-only softmax
  stage_v(0, smem);

  // ---- softmax (per q = lane&15; reduce over the 4 lane-groups) ----
  float mx = -3e38f;
#pragma unroll
  for (int t16 = 0; t16 < 32; ++t16)
#pragma unroll
    for (int j = 0; j < 4; ++j) mx = fmaxf(mx, s[t16][j]);
  mx = fmaxf(mx, __shfl_xor(mx, 16));
  mx = fmaxf(mx, __shfl_xor(mx, 32));
  float rs = 0.f;
#pragma unroll
  for (int t16 = 0; t16 < 32; ++t16)
#pragma unroll
    for (int j = 0; j < 4; ++j) {
      float p = __expf(s[t16][j] - mx);
      s[t16][j] = p;
      rs += p;
    }
  rs += __shfl_xor(rs, 16);
  rs += __shfl_xor(rs, 32);
  const float rinv = 1.0f / rs;
  __syncthreads();   // vT chunk 0 staged

  // ---- Phase B: PV ----
  f32x4 oacc[8];
#pragma unroll
  for (int dt = 0; dt < 8; ++dt) oacc[dt] = (f32x4){0.f, 0.f, 0.f, 0.f};
  const int srcA = c + ((g & 1) << 5);
  const int srcB = srcA + 16;
  const bool lowhalf = (g < 2);
#pragma unroll
  for (int ch = 0; ch < NCH_; ++ch) {
    if (ch + 1 < NCH_) stage_v(ch + 1, smem + KBUF_ * ((ch + 1) & 1));
    const char* buf = smem + KBUF_ * (ch & 1);
#pragma unroll
    for (int q = 0; q < 2; ++q) {            // two 32-key groups per chunk
      int t0 = ch * 4 + 2 * q;
      int a0 = packbf2(s[t0][0], s[t0][1]);
      int a1 = packbf2(s[t0][2], s[t0][3]);
      int b0 = packbf2(s[t0 + 1][0], s[t0 + 1][1]);
      int b1 = packbf2(s[t0 + 1][2], s[t0 + 1][3]);
      int xa0 = __shfl(a0, srcA), xb0 = __shfl(b0, srcA);
      int xa1 = __shfl(a1, srcA), xb1 = __shfl(b1, srcA);
      int ya0 = __shfl(a0, srcB), yb0 = __shfl(b0, srcB);
      int ya1 = __shfl(a1, srcB), yb1 = __shfl(b1, srcB);
      i32x4 ui;
      ui[0] = lowhalf ? xa0 : xb0;
      ui[1] = lowhalf ? xa1 : xb1;
      ui[2] = lowhalf ? ya0 : yb0;
      ui[3] = lowhalf ? ya1 : yb1;
      bf16x8 pf = __builtin_bit_cast(bf16x8, ui);
#pragma unroll
      for (int dt = 0; dt < 8; ++dt) {
        int row = dt * 16 + c;
        bf16x8 vt = *(const bf16x8*)(buf + row * 128 + ((q * 64 + g * 16) ^ ((row & 7) << 4)));
        oacc[dt] = MFMA16(vt, pf, oacc[dt], 0, 0, 0);
      }
    }
    __syncthreads();
  }

  // ---- epilogue ----
  const int qg = q0 + c;
  const bool valid = qg < lq;
  float* orow = o + ((long)(b * N_ + qg)) * D_;
#pragma unroll
  for (int dt = 0; dt < 8; ++dt) {
    f32x4 vo;
#pragma unroll
    for (int j = 0; j < 4; ++j) vo[j] = valid ? oacc[dt][j] * rinv : 0.0f;
    *(f32x4*)(orow + dt * 16 + g * 4) = vo;
  }
}

extern "C" void kernel_launch(void* const* d_in, const int* in_sizes, int n_in,
                              void* d_out, int out_size, void* d_ws, size_t ws_size,
                              hipStream_t stream) {
  const float* h1 = (const float*)d_in[0];
  const float* h2 = (const float*)d_in[1];
  const float* Wk = (const float*)d_in[2];
  const float* bk = (const float*)d_in[3];
  const float* Wq = (const float*)d_in[4];
  const float* bq = (const float*)d_in[5];
  const float* t  = (const float*)d_in[6];
  const int* len1 = (const int*)d_in[7];
  const int* len2 = (const int*)d_in[8];

  char* ws = (char*)d_ws;
  const size_t SZ = (size_t)B_ * N_ * D_ * 2;
  short* k1  = (short*)(ws + 0 * SZ);
  short* k2  = (short*)(ws + 1 * SZ);
  short* q1  = (short*)(ws + 2 * SZ);
  short* q2  = (short*)(ws + 3 * SZ);
  short* k1T = (short*)(ws + 4 * SZ);
  short* k2T = (short*)(ws + 5 * SZ);
  short* wkb = (short*)(ws + 6 * SZ);
  short* wqb = (short*)(ws + 6 * SZ + D_ * D_ * 2);

  prep_w<<<64, 256, 0, stream>>>(Wk, Wq, wkb, wqb);
  proj_kernel<<<512, 256, 0, stream>>>(h1, h2, wkb, wqb, bk, bq,
                                       k1, k2, q1, q2, k1T, k2T);
  attn_kernel<<<dim3(8, 64, 2), 256, 2 * KBUF_, stream>>>(k1, k2, q1, q2, k1T, k2T,
                                                          t, len1, len2, (float*)d_out);
}

// Round 3
// 75.936 us; speedup vs baseline: 2.0453x; 1.1190x over previous
//
#include <hip/hip_runtime.h>

typedef __attribute__((ext_vector_type(8))) short bf16x8;
typedef __attribute__((ext_vector_type(4))) short s16x4;
typedef __attribute__((ext_vector_type(4))) float f32x4;
typedef __attribute__((ext_vector_type(4))) int   i32x4;

#define MFMA16 __builtin_amdgcn_mfma_f32_16x16x32_bf16

#define B_ 64
#define N_ 512
#define D_ 128
#define KBUF_ 16384

__device__ __forceinline__ unsigned short f2bf(float f) {
  unsigned u = __builtin_bit_cast(unsigned, f);
  u += 0x7fffu + ((u >> 16) & 1u);          // round-to-nearest-even
  return (unsigned short)(u >> 16);
}
__device__ __forceinline__ int packbf2(float lo, float hi) {
  return (int)((unsigned)f2bf(lo) | ((unsigned)f2bf(hi) << 16));
}

__device__ __forceinline__ void gload_lds16(const void* g, void* l) {
  __builtin_amdgcn_global_load_lds((const __attribute__((address_space(1))) unsigned*)g,
                                   (__attribute__((address_space(3))) unsigned*)l, 16, 0, 0);
}

// ---------------- W -> bf16 prep ----------------
__global__ void prep_w(const float* __restrict__ Wk, const float* __restrict__ Wq,
                       short* __restrict__ wkb, short* __restrict__ wqb) {
  int i = blockIdx.x * 256 + threadIdx.x;
  if (i < D_ * D_) { wkb[i] = (short)f2bf(Wk[i]); wqb[i] = (short)f2bf(Wq[i]); }
}

// ---------------- projections: k = h@Wk^T+bk, q = h@Wq^T+bq (bf16 out, + kT) ----------------
__global__ __launch_bounds__(256, 2) void proj_kernel(
    const float* __restrict__ h1, const float* __restrict__ h2,
    const short* __restrict__ wkb, const short* __restrict__ wqb,
    const float* __restrict__ bk, const float* __restrict__ bq,
    short* __restrict__ k1, short* __restrict__ k2,
    short* __restrict__ q1, short* __restrict__ q2,
    short* __restrict__ k1T, short* __restrict__ k2T) {
  const int wave = threadIdx.x >> 6, lane = threadIdx.x & 63;
  const int c = lane & 15, g = lane >> 4;
  const int rw = blockIdx.x * 128 + wave * 32;
  const int inp = rw >> 15;
  const int loc = rw & 32767;
  const int b = loc >> 9, n0 = loc & 511;
  const float* __restrict__ h = inp ? h2 : h1;
  short* __restrict__ kout = inp ? k2 : k1;
  short* __restrict__ qout = inp ? q2 : q1;
  short* __restrict__ kT   = inp ? k2T : k1T;

  bf16x8 xf[2][4];
#pragma unroll
  for (int mt = 0; mt < 2; ++mt) {
    const float* hr = h + (long)(loc + mt * 16 + c) * D_;
#pragma unroll
    for (int kk = 0; kk < 4; ++kk) {
      f32x4 lo = *(const f32x4*)(hr + kk * 32 + g * 8);
      f32x4 hi = *(const f32x4*)(hr + kk * 32 + g * 8 + 4);
      bf16x8 v;
      v[0] = (short)f2bf(lo[0]); v[1] = (short)f2bf(lo[1]);
      v[2] = (short)f2bf(lo[2]); v[3] = (short)f2bf(lo[3]);
      v[4] = (short)f2bf(hi[0]); v[5] = (short)f2bf(hi[1]);
      v[6] = (short)f2bf(hi[2]); v[7] = (short)f2bf(hi[3]);
      xf[mt][kk] = v;
    }
  }

#pragma unroll
  for (int et = 0; et < 8; ++et) {
    bf16x8 wkf[4], wqf[4];
    const short* wkr = wkb + (et * 16 + c) * D_;
    const short* wqr = wqb + (et * 16 + c) * D_;
#pragma unroll
    for (int kk = 0; kk < 4; ++kk) {
      wkf[kk] = *(const bf16x8*)(wkr + kk * 32 + g * 8);
      wqf[kk] = *(const bf16x8*)(wqr + kk * 32 + g * 8);
    }
    f32x4 ak[2], aq[2], at[2];
#pragma unroll
    for (int mt = 0; mt < 2; ++mt) {
      ak[mt] = (f32x4){0.f, 0.f, 0.f, 0.f};
      aq[mt] = (f32x4){0.f, 0.f, 0.f, 0.f};
      at[mt] = (f32x4){0.f, 0.f, 0.f, 0.f};
    }
#pragma unroll
    for (int kk = 0; kk < 4; ++kk) {
#pragma unroll
      for (int mt = 0; mt < 2; ++mt) {
        ak[mt] = MFMA16(wkf[kk], xf[mt][kk], ak[mt], 0, 0, 0);
        aq[mt] = MFMA16(wqf[kk], xf[mt][kk], aq[mt], 0, 0, 0);
        at[mt] = MFMA16(xf[mt][kk], wkf[kk], at[mt], 0, 0, 0);
      }
    }
    f32x4 bkv = *(const f32x4*)(bk + et * 16 + g * 4);
    f32x4 bqv = *(const f32x4*)(bq + et * 16 + g * 4);
    float bks = bk[et * 16 + c];
#pragma unroll
    for (int mt = 0; mt < 2; ++mt) {
      s16x4 pk, pq, pt;
#pragma unroll
      for (int j = 0; j < 4; ++j) {
        pk[j] = (short)f2bf(ak[mt][j] + bkv[j]);
        pq[j] = (short)f2bf(aq[mt][j] + bqv[j]);
        pt[j] = (short)f2bf(at[mt][j] + bks);
      }
      long row = (long)(loc + mt * 16 + c);
      *(s16x4*)(kout + row * D_ + et * 16 + g * 4) = pk;
      *(s16x4*)(qout + row * D_ + et * 16 + g * 4) = pq;
      *(s16x4*)(kT + ((long)(b * D_ + et * 16 + c)) * N_ + n0 + mt * 16 + g * 4) = pt;
    }
  }
}

// ---------------- attention (triple-buffered counted-vmcnt pipeline) ----------------
// 1D grid 1024: qt = wgid>>7, bd = wgid&127 -> blocks sharing (b,dir) are 128 apart
// (same XCD under round-robin). 16 chunks: 0-7 = K (64 rows x 256B), 8-15 = vT
// (128 rows x 128B). Chunk i lives in buffer i%3; 2 chunks always in flight.
__global__ __launch_bounds__(256, 2) void attn_kernel(
    const short* __restrict__ k1, const short* __restrict__ k2,
    const short* __restrict__ q1, const short* __restrict__ q2,
    const short* __restrict__ k1T, const short* __restrict__ k2T,
    const float* __restrict__ tptr,
    const int* __restrict__ len1, const int* __restrict__ len2,
    float* __restrict__ out) {
  extern __shared__ char smem[];
  const int tid = threadIdx.x;
  const int wave = tid >> 6, lane = tid & 63;
  const int c = lane & 15, g = lane >> 4;
  const int wgid = blockIdx.x;
  const int qt = wgid >> 7;
  const int bd = wgid & 127;
  const int dir = bd >> 6, b = bd & 63;
  const short* __restrict__ qp = dir ? q2 : q1;
  const short* __restrict__ kp = dir ? k1 : k2;
  const short* __restrict__ vT = dir ? k1T : k2T;
  const int lk = dir ? len1[b] : len2[b];
  const int lq = dir ? len2[b] : len1[b];
  float* __restrict__ o = out + (long)dir * B_ * N_ * D_;
  const float ts = *tptr;
  const int q0 = qt * 64 + wave * 16;

  const char* kbase = (const char*)(kp + (long)b * N_ * D_);   // [512][256B]
  const char* vbase = (const char*)(vT + (long)b * D_ * N_);   // [128][1024B]

  // stage chunk i (compile-time i in all call sites -> branches fold)
  auto stage = [&](int i) {
    char* buf = smem + KBUF_ * (i % 3);
    if (i < 8) {
#pragma unroll
      for (int j = 0; j < 4; ++j) {
        int L = j * 4096 + tid * 16;
        int row = L >> 8, off = L & 255;
        const char* gp = kbase + (i * 64 + row) * 256 + (off ^ ((row & 7) << 4));
        gload_lds16(gp, buf + j * 4096 + (wave << 10));
      }
    } else {
      int ch = i - 8;
#pragma unroll
      for (int j = 0; j < 4; ++j) {
        int L = j * 4096 + tid * 16;
        int row = L >> 7, off = L & 127;
        const char* gp = vbase + row * 1024 + ch * 128 + (off ^ ((row & 7) << 4));
        gload_lds16(gp, buf + j * 4096 + (wave << 10));
      }
    }
  };

  // Q fragments (lane=q-row) -- issued before the stages; any vmcnt(4) below
  // implies these have landed.
  bf16x8 qf[4];
  const short* qrow = qp + ((long)(b * N_ + q0 + c)) * D_;
#pragma unroll
  for (int kk = 0; kk < 4; ++kk) qf[kk] = *(const bf16x8*)(qrow + kk * 32 + g * 8);

  stage(0);
  stage(1);

  // ---- Phase A: S^T over 8 K-chunks ----
  f32x4 s[32];
#pragma unroll
  for (int ch = 0; ch < 8; ++ch) {
    asm volatile("s_waitcnt vmcnt(4)" ::: "memory");   // chunk ch landed (wave-local)
    __builtin_amdgcn_sched_barrier(0);
    __builtin_amdgcn_s_barrier();                      // all waves' ch landed; prev compute done
    __builtin_amdgcn_sched_barrier(0);
    stage(ch + 2);                                     // overwrite buffer of ch-1 (safe post-barrier)
    const char* buf = smem + KBUF_ * (ch % 3);
    __builtin_amdgcn_s_setprio(1);
#pragma unroll
    for (int tl = 0; tl < 4; ++tl) {
      int r = tl * 16 + c;
      const char* base = buf + (r << 8);
      int sw = (r & 7) << 4;
      f32x4 acc = (f32x4){0.f, 0.f, 0.f, 0.f};
#pragma unroll
      for (int kk = 0; kk < 4; ++kk) {
        bf16x8 kf = *(const bf16x8*)(base + ((kk * 64 + g * 16) ^ sw));
        acc = MFMA16(kf, qf[kk], acc, 0, 0, 0);
      }
      const int node = ch * 64 + tl * 16 + g * 4;
#pragma unroll
      for (int j = 0; j < 4; ++j) {
        float v = acc[j] * ts;
        s[ch * 4 + tl][j] = (node + j < lk) ? v : -1e9f;
      }
    }
    __builtin_amdgcn_s_setprio(0);
  }

  // ---- softmax (register-only; V0/V1 DMAs in flight underneath) ----
  float mx = -3e38f;
#pragma unroll
  for (int t16 = 0; t16 < 32; ++t16)
#pragma unroll
    for (int j = 0; j < 4; ++j) mx = fmaxf(mx, s[t16][j]);
  mx = fmaxf(mx, __shfl_xor(mx, 16));
  mx = fmaxf(mx, __shfl_xor(mx, 32));
  float rs = 0.f;
#pragma unroll
  for (int t16 = 0; t16 < 32; ++t16)
#pragma unroll
    for (int j = 0; j < 4; ++j) {
      float p = __expf(s[t16][j] - mx);
      s[t16][j] = p;
      rs += p;
    }
  rs += __shfl_xor(rs, 16);
  rs += __shfl_xor(rs, 32);
  const float rinv = 1.0f / rs;

  // ---- Phase B: PV over 8 vT-chunks ----
  f32x4 oacc[8];
#pragma unroll
  for (int dt = 0; dt < 8; ++dt) oacc[dt] = (f32x4){0.f, 0.f, 0.f, 0.f};
  const int srcA = c + ((g & 1) << 5);
  const int srcB = srcA + 16;
  const bool lowhalf = (g < 2);
#pragma unroll
  for (int ch = 0; ch < 8; ++ch) {
    if (ch == 7) asm volatile("s_waitcnt vmcnt(0)" ::: "memory");
    else         asm volatile("s_waitcnt vmcnt(4)" ::: "memory");
    __builtin_amdgcn_sched_barrier(0);
    __builtin_amdgcn_s_barrier();
    __builtin_amdgcn_sched_barrier(0);
    if (ch + 10 < 16) stage(ch + 10);
    const char* buf = smem + KBUF_ * ((ch + 8) % 3);
#pragma unroll
    for (int q = 0; q < 2; ++q) {
      int t0 = ch * 4 + 2 * q;
      int a0 = packbf2(s[t0][0], s[t0][1]);
      int a1 = packbf2(s[t0][2], s[t0][3]);
      int b0 = packbf2(s[t0 + 1][0], s[t0 + 1][1]);
      int b1 = packbf2(s[t0 + 1][2], s[t0 + 1][3]);
      int xa0 = __shfl(a0, srcA), xb0 = __shfl(b0, srcA);
      int xa1 = __shfl(a1, srcA), xb1 = __shfl(b1, srcA);
      int ya0 = __shfl(a0, srcB), yb0 = __shfl(b0, srcB);
      int ya1 = __shfl(a1, srcB), yb1 = __shfl(b1, srcB);
      i32x4 ui;
      ui[0] = lowhalf ? xa0 : xb0;
      ui[1] = lowhalf ? xa1 : xb1;
      ui[2] = lowhalf ? ya0 : yb0;
      ui[3] = lowhalf ? ya1 : yb1;
      bf16x8 pf = __builtin_bit_cast(bf16x8, ui);
      __builtin_amdgcn_s_setprio(1);
#pragma unroll
      for (int dt = 0; dt < 8; ++dt) {
        int row = dt * 16 + c;
        bf16x8 vt = *(const bf16x8*)(buf + row * 128 + ((q * 64 + g * 16) ^ ((row & 7) << 4)));
        oacc[dt] = MFMA16(vt, pf, oacc[dt], 0, 0, 0);
      }
      __builtin_amdgcn_s_setprio(0);
    }
  }

  // ---- epilogue ----
  const int qg = q0 + c;
  const bool valid = qg < lq;
  float* orow = o + ((long)(b * N_ + qg)) * D_;
#pragma unroll
  for (int dt = 0; dt < 8; ++dt) {
    f32x4 vo;
#pragma unroll
    for (int j = 0; j < 4; ++j) vo[j] = valid ? oacc[dt][j] * rinv : 0.0f;
    *(f32x4*)(orow + dt * 16 + g * 4) = vo;
  }
}

extern "C" void kernel_launch(void* const* d_in, const int* in_sizes, int n_in,
                              void* d_out, int out_size, void* d_ws, size_t ws_size,
                              hipStream_t stream) {
  const float* h1 = (const float*)d_in[0];
  const float* h2 = (const float*)d_in[1];
  const float* Wk = (const float*)d_in[2];
  const float* bk = (const float*)d_in[3];
  const float* Wq = (const float*)d_in[4];
  const float* bq = (const float*)d_in[5];
  const float* t  = (const float*)d_in[6];
  const int* len1 = (const int*)d_in[7];
  const int* len2 = (const int*)d_in[8];

  char* ws = (char*)d_ws;
  const size_t SZ = (size_t)B_ * N_ * D_ * 2;
  short* k1  = (short*)(ws + 0 * SZ);
  short* k2  = (short*)(ws + 1 * SZ);
  short* q1  = (short*)(ws + 2 * SZ);
  short* q2  = (short*)(ws + 3 * SZ);
  short* k1T = (short*)(ws + 4 * SZ);
  short* k2T = (short*)(ws + 5 * SZ);
  short* wkb = (short*)(ws + 6 * SZ);
  short* wqb = (short*)(ws + 6 * SZ + D_ * D_ * 2);

  prep_w<<<64, 256, 0, stream>>>(Wk, Wq, wkb, wqb);
  proj_kernel<<<512, 256, 0, stream>>>(h1, h2, wkb, wqb, bk, bq,
                                       k1, k2, q1, q2, k1T, k2T);
  attn_kernel<<<1024, 256, 3 * KBUF_, stream>>>(k1, k2, q1, q2, k1T, k2T,
                                                t, len1, len2, (float*)d_out);
}